// Round 1
// baseline (236.397 us; speedup 1.0000x reference)
//
#include <hip/hip_runtime.h>

// MedianBlur 3x3, zero padding, input [8,16,512,512] f32 -> same shape f32.
// H = W = 512 hardcoded (fixed problem shape). 128 planes (B*C).

#define WD 512
#define HT 512
#define PLANE (WD * HT)

__device__ __forceinline__ void s2(float& a, float& b) {
    float t = fminf(a, b);
    b = fmaxf(a, b);
    a = t;
}

// Classic 19-exchange median-of-9 network (Paeth / Smith).
__device__ __forceinline__ float med9(float p0, float p1, float p2,
                                      float p3, float p4, float p5,
                                      float p6, float p7, float p8) {
    s2(p1, p2); s2(p4, p5); s2(p7, p8);
    s2(p0, p1); s2(p3, p4); s2(p6, p7);
    s2(p1, p2); s2(p4, p5); s2(p7, p8);
    s2(p0, p3); s2(p5, p8); s2(p4, p7);
    s2(p3, p6); s2(p1, p4); s2(p2, p5);
    s2(p4, p7); s2(p4, p2); s2(p6, p4);
    s2(p4, p2);
    return p4;
}

__global__ __launch_bounds__(256)
void medblur3x3(const float* __restrict__ in, float* __restrict__ out) {
    int t = blockIdx.x * blockDim.x + threadIdx.x;
    // 4 pixels per thread; PLANE/4 = 65536 threads per plane.
    int plane = t >> 16;
    int idx   = (t & 0xFFFF) << 2;   // pixel index within plane, multiple of 4
    int h  = idx >> 9;               // row (W = 512)
    int w0 = idx & 511;              // col of first pixel (multiple of 4)

    const float* base = in + (long)plane * PLANE;

    // r[dr][0..5] = columns w0-1 .. w0+4 of row h+dr-1 (zero padded)
    float r[3][6];
#pragma unroll
    for (int dr = 0; dr < 3; ++dr) {
        int hh = h + dr - 1;
        if (hh < 0 || hh >= HT) {
#pragma unroll
            for (int j = 0; j < 6; ++j) r[dr][j] = 0.0f;
        } else {
            const float* row = base + hh * WD;
            float4 c = *reinterpret_cast<const float4*>(row + w0);
            r[dr][1] = c.x; r[dr][2] = c.y; r[dr][3] = c.z; r[dr][4] = c.w;
            r[dr][0] = (w0 == 0)        ? 0.0f : row[w0 - 1];
            r[dr][5] = (w0 == WD - 4)   ? 0.0f : row[w0 + 4];
        }
    }

    float4 o;
    o.x = med9(r[0][0], r[0][1], r[0][2],
               r[1][0], r[1][1], r[1][2],
               r[2][0], r[2][1], r[2][2]);
    o.y = med9(r[0][1], r[0][2], r[0][3],
               r[1][1], r[1][2], r[1][3],
               r[2][1], r[2][2], r[2][3]);
    o.z = med9(r[0][2], r[0][3], r[0][4],
               r[1][2], r[1][3], r[1][4],
               r[2][2], r[2][3], r[2][4]);
    o.w = med9(r[0][3], r[0][4], r[0][5],
               r[1][3], r[1][4], r[1][5],
               r[2][3], r[2][4], r[2][5]);

    *reinterpret_cast<float4*>(out + (long)plane * PLANE + idx) = o;
}

extern "C" void kernel_launch(void* const* d_in, const int* in_sizes, int n_in,
                              void* d_out, int out_size, void* d_ws, size_t ws_size,
                              hipStream_t stream) {
    const float* x = (const float*)d_in[0];
    float* out = (float*)d_out;

    int nthreads = out_size / 4;            // 8,388,608 threads
    int block = 256;
    int grid = nthreads / block;            // 32,768 blocks (exact)
    medblur3x3<<<grid, block, 0, stream>>>(x, out);
}

// Round 2
// 225.682 us; speedup vs baseline: 1.0475x; 1.0475x over previous
//
#include <hip/hip_runtime.h>

// MedianBlur 3x3, zero padding, input [8,16,512,512] f32 -> same shape f32.
// One wave (64 lanes) = one full image row (64 * 8 px = 512).
// Separable median: per-column (lo,mid,hi) via v_min3/med3/max3, shared
// across horizontal neighbors; lane-edge columns via shuffle (wave edge ==
// image edge == zero pad).

#define WD 512
#define HT 512
#define PLANE (WD * HT)

__device__ __forceinline__ float min3f(float a, float b, float c) { return fminf(fminf(a, b), c); }
__device__ __forceinline__ float max3f(float a, float b, float c) { return fmaxf(fmaxf(a, b), c); }
__device__ __forceinline__ float med3f(float a, float b, float c) { return __builtin_amdgcn_fmed3f(a, b, c); }

__global__ __launch_bounds__(256)
void medblur3x3(const float* __restrict__ in, float* __restrict__ out) {
    int g = blockIdx.x * blockDim.x + threadIdx.x;
    int lane  = g & 63;
    int wave  = g >> 6;          // 0 .. 65535
    int row   = wave & (HT - 1); // one row per wave
    int plane = wave >> 9;       // 0 .. 127
    int w0 = lane << 3;          // first of this lane's 8 columns

    const float* base = in + (long)plane * PLANE;

    // v[dr][j]: rows row-1..row+1 (zero padded), columns w0..w0+7
    float v[3][8];
#pragma unroll
    for (int dr = 0; dr < 3; ++dr) {
        int hh = row + dr - 1;
        if (hh >= 0 && hh < HT) {
            const float4* rp = reinterpret_cast<const float4*>(base + hh * WD + w0);
            float4 a = rp[0], b = rp[1];
            v[dr][0] = a.x; v[dr][1] = a.y; v[dr][2] = a.z; v[dr][3] = a.w;
            v[dr][4] = b.x; v[dr][5] = b.y; v[dr][6] = b.z; v[dr][7] = b.w;
        } else {
#pragma unroll
            for (int j = 0; j < 8; ++j) v[dr][j] = 0.0f;
        }
    }

    // Column triples (sorted vertical 3-tuples), extended with neighbors:
    // index 0 = column w0-1 (from lane-1), 1..8 = own, 9 = column w0+8 (lane+1)
    float lo[10], mi[10], hi[10];
#pragma unroll
    for (int j = 0; j < 8; ++j) {
        lo[j + 1] = min3f(v[0][j], v[1][j], v[2][j]);
        mi[j + 1] = med3f(v[0][j], v[1][j], v[2][j]);
        hi[j + 1] = max3f(v[0][j], v[1][j], v[2][j]);
    }
    lo[0] = __shfl_up(lo[8], 1, 64);
    mi[0] = __shfl_up(mi[8], 1, 64);
    hi[0] = __shfl_up(hi[8], 1, 64);
    lo[9] = __shfl_down(lo[1], 1, 64);
    mi[9] = __shfl_down(mi[1], 1, 64);
    hi[9] = __shfl_down(hi[1], 1, 64);
    if (lane == 0)  { lo[0] = 0.0f; mi[0] = 0.0f; hi[0] = 0.0f; }  // image left edge
    if (lane == 63) { lo[9] = 0.0f; mi[9] = 0.0f; hi[9] = 0.0f; }  // image right edge

    // median9 = med3( max(los), med(mids), min(his) )
    float o[8];
#pragma unroll
    for (int j = 0; j < 8; ++j) {
        float a = max3f(lo[j], lo[j + 1], lo[j + 2]);
        float b = med3f(mi[j], mi[j + 1], mi[j + 2]);
        float c = min3f(hi[j], hi[j + 1], hi[j + 2]);
        o[j] = med3f(a, b, c);
    }

    float* op = out + (long)plane * PLANE + row * WD + w0;
    reinterpret_cast<float4*>(op)[0] = make_float4(o[0], o[1], o[2], o[3]);
    reinterpret_cast<float4*>(op)[1] = make_float4(o[4], o[5], o[6], o[7]);
}

extern "C" void kernel_launch(void* const* d_in, const int* in_sizes, int n_in,
                              void* d_out, int out_size, void* d_ws, size_t ws_size,
                              hipStream_t stream) {
    const float* x = (const float*)d_in[0];
    float* out = (float*)d_out;

    int nthreads = out_size / 8;            // 4,194,304 threads
    int block = 256;
    int grid = nthreads / block;            // 16,384 blocks (exact)
    medblur3x3<<<grid, block, 0, stream>>>(x, out);
}